// Round 1
// baseline (1102.460 us; speedup 1.0000x reference)
//
#include <hip/hip_runtime.h>

#define FEAT 64

// ---------------------------------------------------------------------------
// Detect whether edge_index is int64 (odd 32-bit words of first row all zero)
// or int32. Writes flag (1 = int64) into workspace so no host sync is needed.
// ---------------------------------------------------------------------------
__global__ void detect_idx_kernel(const unsigned* __restrict__ w, int* __restrict__ flag) {
    __shared__ int any_nonzero;
    if (threadIdx.x == 0) any_nonzero = 0;
    __syncthreads();
    unsigned v = w[2 * threadIdx.x + 1];   // stays within first 2KB of either layout
    if (v != 0u) atomicOr(&any_nonzero, 1);
    __syncthreads();
    if (threadIdx.x == 0) *flag = (any_nonzero == 0) ? 1 : 0;
}

__device__ __forceinline__ int load_idx(const void* ei, long long i, int is64) {
    if (is64) return (int)((const long long*)ei)[i];
    return ((const int*)ei)[i];
}

// ---------------------------------------------------------------------------
// Degree: one thread per edge, atomicAdd 1.0f at dst.
// ---------------------------------------------------------------------------
__global__ void deg_kernel(const void* __restrict__ ei, const int* __restrict__ flagp,
                           float* __restrict__ deg, int n_edges) {
    int e = blockIdx.x * blockDim.x + threadIdx.x;
    if (e >= n_edges) return;
    int is64 = *flagp;
    int d = load_idx(ei, (long long)n_edges + e, is64);
    atomicAdd(&deg[d], 1.0f);
}

__global__ void deginv_kernel(float* __restrict__ deg, int n_nodes) {
    int i = blockIdx.x * blockDim.x + threadIdx.x;
    if (i < n_nodes) deg[i] = 1.0f / fmaxf(deg[i], 1.0f);
}

// ---------------------------------------------------------------------------
// Edge scatter: wave per edge (64 lanes = 64 features). Index loads are
// wave-uniform; feat row read and msg atomicAdd row are 256B coalesced.
// ---------------------------------------------------------------------------
__global__ __launch_bounds__(256)
void scatter_kernel(const float* __restrict__ feat, const void* __restrict__ ei,
                    const int* __restrict__ flagp, float* __restrict__ msg, int n_edges) {
    int e = blockIdx.x * 4 + (threadIdx.x >> 6);
    if (e >= n_edges) return;
    int f = threadIdx.x & 63;
    int is64 = *flagp;
    int s = load_idx(ei, e, is64);
    int d = load_idx(ei, (long long)n_edges + e, is64);
    atomicAdd(&msg[(long long)d * FEAT + f], feat[(long long)s * FEAT + f]);
}

// ---------------------------------------------------------------------------
// Fused per-node SAGE linear: out[n] = act( (msg[n]*deg_inv[n]) @ Wl^T + b
//                                           + self[n] @ Wr^T )
// W staged transposed with +1-pad row (65) -> conflict-free LDS reads.
// Block = 256 threads = 4 nodes x 64 out-features; grid-stride over groups.
// ---------------------------------------------------------------------------
__global__ __launch_bounds__(256)
void sage_linear_kernel(const float* __restrict__ msg, const float* __restrict__ self_feat,
                        const float* __restrict__ deg_inv,
                        const float* __restrict__ Wl, const float* __restrict__ bias,
                        const float* __restrict__ Wr,
                        float* __restrict__ out, int do_relu, int n_nodes) {
    __shared__ float WlT[FEAT * 65];
    __shared__ float WrT[FEAT * 65];
    __shared__ float bsh[FEAT];
    __shared__ float aggS[4][FEAT];
    __shared__ float selfS[4][FEAT];

    const int t = threadIdx.x;
    // Stage weights transposed: WlT[k*65 + j] = Wl[j*64 + k]
    #pragma unroll
    for (int p = 0; p < 16; ++p) {
        int i = t + p * 256;
        int j = i >> 6, k = i & 63;
        WlT[k * 65 + j] = Wl[i];
        WrT[k * 65 + j] = Wr[i];
    }
    if (t < FEAT) bsh[t] = bias[t];

    const int nl = t >> 6;     // node within group (0..3)
    const int j  = t & 63;     // output feature
    const int n_groups = (n_nodes + 3) >> 2;

    for (int g = blockIdx.x; g < n_groups; g += gridDim.x) {
        int n = g * 4 + nl;
        __syncthreads();       // protects LDS rows from previous iteration (and W on iter 0)
        if (n < n_nodes) {
            float di = deg_inv[n];
            aggS[nl][j]  = msg[(long long)n * FEAT + j] * di;
            selfS[nl][j] = self_feat[(long long)n * FEAT + j];
        }
        __syncthreads();
        if (n < n_nodes) {
            float acc = bsh[j];
            #pragma unroll
            for (int k = 0; k < FEAT; ++k) {
                acc = fmaf(aggS[nl][k],  WlT[k * 65 + j], acc);
                acc = fmaf(selfS[nl][k], WrT[k * 65 + j], acc);
            }
            if (do_relu) acc = fmaxf(acc, 0.0f);
            out[(long long)n * FEAT + j] = acc;
        }
    }
}

// ---------------------------------------------------------------------------
// Launch
// ---------------------------------------------------------------------------
extern "C" void kernel_launch(void* const* d_in, const int* in_sizes, int n_in,
                              void* d_out, int out_size, void* d_ws, size_t ws_size,
                              hipStream_t stream) {
    const float* x   = (const float*)d_in[0];
    const void*  ei  = d_in[1];
    const float* W1l = (const float*)d_in[2];
    const float* b1  = (const float*)d_in[3];
    const float* W1r = (const float*)d_in[4];
    const float* W2l = (const float*)d_in[5];
    const float* b2  = (const float*)d_in[6];
    const float* W2r = (const float*)d_in[7];
    float* out = (float*)d_out;

    const int n_nodes = in_sizes[0] / FEAT;
    const int n_edges = in_sizes[1] / 2;

    // Workspace layout: [flag(256B)] [deg (n_nodes f32, 256B-aligned)] [msg (n_nodes*64 f32)]
    char* ws = (char*)d_ws;
    int*   flag = (int*)ws;
    size_t degB = (((size_t)n_nodes * 4) + 255) & ~(size_t)255;
    float* deg  = (float*)(ws + 256);
    float* msg  = (float*)(ws + 256 + degB);
    size_t msgB = (size_t)n_nodes * FEAT * sizeof(float);

    // h (layer-1 output) lives in d_out and is consumed/overwritten in place by layer 2.
    float* h = out;

    hipMemsetAsync(deg, 0, (size_t)n_nodes * 4, stream);
    hipMemsetAsync(msg, 0, msgB, stream);

    detect_idx_kernel<<<1, 256, 0, stream>>>((const unsigned*)ei, flag);

    deg_kernel<<<(n_edges + 255) / 256, 256, 0, stream>>>(ei, flag, deg, n_edges);
    deginv_kernel<<<(n_nodes + 255) / 256, 256, 0, stream>>>(deg, n_nodes);

    // Layer 1
    scatter_kernel<<<(n_edges + 3) / 4, 256, 0, stream>>>(x, ei, flag, msg, n_edges);
    int n_groups = (n_nodes + 3) / 4;
    int lin_grid = n_groups < 1024 ? n_groups : 1024;
    sage_linear_kernel<<<lin_grid, 256, 0, stream>>>(msg, x, deg, W1l, b1, W1r, h, 1, n_nodes);

    // Layer 2
    hipMemsetAsync(msg, 0, msgB, stream);
    scatter_kernel<<<(n_edges + 3) / 4, 256, 0, stream>>>(h, ei, flag, msg, n_edges);
    sage_linear_kernel<<<lin_grid, 256, 0, stream>>>(msg, h, deg, W2l, b2, W2r, out, 0, n_nodes);
}

// Round 3
// 728.517 us; speedup vs baseline: 1.5133x; 1.5133x over previous
//
#include <hip/hip_runtime.h>
#include <hip/hip_bf16.h>

#define FEAT 64

// ---------------------------------------------------------------------------
// Zero int buffers via kernel (NOT hipMemsetAsync: memset may execute at
// graph-capture time instead of being recorded -> poisoned on replay).
// ---------------------------------------------------------------------------
__global__ __launch_bounds__(256)
void zero2_kernel(int* __restrict__ a, int* __restrict__ b, int n) {
    int i = blockIdx.x * 256 + threadIdx.x;
    if (i < n) { a[i] = 0; b[i] = 0; }
}

// ---------------------------------------------------------------------------
// int64-vs-int32 edge_index sniffer (flag=1 if int64): for int64 data the
// high (odd) 32-bit words of the first 256 src values are all zero.
// ---------------------------------------------------------------------------
__global__ void detect_idx_kernel(const unsigned* __restrict__ w, int* __restrict__ flag) {
    __shared__ int any_nz;
    if (threadIdx.x == 0) any_nz = 0;
    __syncthreads();
    if (w[2 * threadIdx.x + 1] != 0u) atomicOr(&any_nz, 1);  // first 2KB only
    __syncthreads();
    if (threadIdx.x == 0) *flag = (any_nz == 0) ? 1 : 0;
}

__device__ __forceinline__ int load_idx_clamped(const void* ei, long long i, int is64, int n_nodes) {
    int v = is64 ? (int)((const long long*)ei)[i] : ((const int*)ei)[i];
    v = v < 0 ? 0 : v;
    return v >= n_nodes ? n_nodes - 1 : v;   // identity when data is sane
}

// ---------------------------------------------------------------------------
// CSR build: histogram -> block partials -> top scan -> final scan -> scatter
// ---------------------------------------------------------------------------
__global__ __launch_bounds__(256)
void hist_kernel(const void* __restrict__ ei, const int* __restrict__ flagp,
                 int* __restrict__ degc, int n_edges, int n_nodes) {
    int e = blockIdx.x * 256 + threadIdx.x;
    if (e >= n_edges) return;
    int d = load_idx_clamped(ei, (long long)n_edges + e, *flagp, n_nodes);
    atomicAdd(&degc[d], 1);
}

__global__ __launch_bounds__(256)
void scan_partial_kernel(const int* __restrict__ degc, int* __restrict__ part, int n_nodes) {
    __shared__ int sh[256];
    int i = blockIdx.x * 256 + threadIdx.x;
    sh[threadIdx.x] = (i < n_nodes) ? degc[i] : 0;
    __syncthreads();
    for (int off = 128; off > 0; off >>= 1) {
        if (threadIdx.x < off) sh[threadIdx.x] += sh[threadIdx.x + off];
        __syncthreads();
    }
    if (threadIdx.x == 0) part[blockIdx.x] = sh[0];
}

__global__ void scan_top_kernel(int* __restrict__ part, int nparts) {
    __shared__ int sh[512];
    int t = threadIdx.x;
    int v = (t < nparts) ? part[t] : 0;
    sh[t] = v;
    __syncthreads();
    for (int off = 1; off < 512; off <<= 1) {
        int u = (t >= off) ? sh[t - off] : 0;
        __syncthreads();
        sh[t] += u;
        __syncthreads();
    }
    if (t < nparts) part[t] = sh[t] - v;   // exclusive
}

__global__ __launch_bounds__(256)
void scan_final_kernel(const int* __restrict__ degc, const int* __restrict__ part,
                       int* __restrict__ offs, float* __restrict__ deg_inv, int n_nodes) {
    __shared__ int sh[256];
    int t = threadIdx.x;
    int i = blockIdx.x * 256 + t;
    int v = (i < n_nodes) ? degc[i] : 0;
    sh[t] = v;
    __syncthreads();
    for (int off = 1; off < 256; off <<= 1) {
        int u = (t >= off) ? sh[t - off] : 0;
        __syncthreads();
        sh[t] += u;
        __syncthreads();
    }
    if (i < n_nodes) {
        offs[i]    = sh[t] - v + part[blockIdx.x];
        deg_inv[i] = 1.0f / fmaxf((float)v, 1.0f);
    }
}

__global__ __launch_bounds__(256)
void csr_scatter_kernel(const void* __restrict__ ei, const int* __restrict__ flagp,
                        const int* __restrict__ offs, int* __restrict__ cursor,
                        int* __restrict__ csr, int n_edges, int n_nodes) {
    int e = blockIdx.x * 256 + threadIdx.x;
    if (e >= n_edges) return;
    int is64 = *flagp;
    int s = load_idx_clamped(ei, e, is64, n_nodes);
    int d = load_idx_clamped(ei, (long long)n_edges + e, is64, n_nodes);
    int pos = offs[d] + atomicAdd(&cursor[d], 1);
    pos = pos < 0 ? 0 : (pos >= n_edges ? n_edges - 1 : pos);  // identity when sane
    csr[pos] = s;
}

// ---------------------------------------------------------------------------
// Fused SAGE layer: wave per node (lane = feature). Neighbor ids loaded
// coalesced 64-at-a-time, broadcast via __shfl; gather-sum -> mean -> fused
// 64x64 linears from LDS-staged transposed weights (+1 pad, conflict-free).
// Layer 1: f32 in, bf16 out (+ReLU).  Layer 2: bf16 in, f32 out.
// ---------------------------------------------------------------------------
__global__ __launch_bounds__(256)
void sage_fused_l1_kernel(const float* __restrict__ xin,
                          const int* __restrict__ offs, const int* __restrict__ degc,
                          const float* __restrict__ deg_inv, const int* __restrict__ csr,
                          const float* __restrict__ Wl, const float* __restrict__ bias,
                          const float* __restrict__ Wr,
                          __hip_bfloat16* __restrict__ hout, int n_nodes) {
    __shared__ float WlT[FEAT * 65], WrT[FEAT * 65], bsh[FEAT];
    __shared__ float aggS[4][FEAT], selfS[4][FEAT];
    const int t = threadIdx.x;
    #pragma unroll
    for (int p = 0; p < 16; ++p) {
        int i = t + p * 256, j = i >> 6, k = i & 63;
        WlT[k * 65 + j] = Wl[i];
        WrT[k * 65 + j] = Wr[i];
    }
    if (t < FEAT) bsh[t] = bias[t];
    __syncthreads();

    const int w = t >> 6, f = t & 63;
    const int n_groups = (n_nodes + 3) >> 2;
    for (int g = blockIdx.x; g < n_groups; g += gridDim.x) {
        int n = g * 4 + w;
        bool act = (n < n_nodes);
        if (act) {
            int rs = offs[n], cnt = degc[n];
            float acc = 0.f;
            for (int c = 0; c < cnt; c += 64) {
                int chunk = min(64, cnt - c);
                int myid = (f < chunk) ? csr[rs + c + f] : 0;
                #pragma unroll 4
                for (int q = 0; q < chunk; ++q) {
                    int s = __shfl(myid, q);
                    acc += xin[(long long)s * FEAT + f];
                }
            }
            aggS[w][f]  = acc * deg_inv[n];
            selfS[w][f] = xin[(long long)n * FEAT + f];
        }
        __syncthreads();
        if (act) {
            float o = bsh[f];
            #pragma unroll
            for (int k = 0; k < FEAT; ++k) {
                o = fmaf(aggS[w][k],  WlT[k * 65 + f], o);
                o = fmaf(selfS[w][k], WrT[k * 65 + f], o);
            }
            o = fmaxf(o, 0.f);
            hout[(long long)n * FEAT + f] = __float2bfloat16(o);
        }
        __syncthreads();
    }
}

__global__ __launch_bounds__(256)
void sage_fused_l2_kernel(const __hip_bfloat16* __restrict__ hin,
                          const int* __restrict__ offs, const int* __restrict__ degc,
                          const float* __restrict__ deg_inv, const int* __restrict__ csr,
                          const float* __restrict__ Wl, const float* __restrict__ bias,
                          const float* __restrict__ Wr,
                          float* __restrict__ out, int n_nodes) {
    __shared__ float WlT[FEAT * 65], WrT[FEAT * 65], bsh[FEAT];
    __shared__ float aggS[4][FEAT], selfS[4][FEAT];
    const int t = threadIdx.x;
    #pragma unroll
    for (int p = 0; p < 16; ++p) {
        int i = t + p * 256, j = i >> 6, k = i & 63;
        WlT[k * 65 + j] = Wl[i];
        WrT[k * 65 + j] = Wr[i];
    }
    if (t < FEAT) bsh[t] = bias[t];
    __syncthreads();

    const int w = t >> 6, f = t & 63;
    const int n_groups = (n_nodes + 3) >> 2;
    for (int g = blockIdx.x; g < n_groups; g += gridDim.x) {
        int n = g * 4 + w;
        bool act = (n < n_nodes);
        if (act) {
            int rs = offs[n], cnt = degc[n];
            float acc = 0.f;
            for (int c = 0; c < cnt; c += 64) {
                int chunk = min(64, cnt - c);
                int myid = (f < chunk) ? csr[rs + c + f] : 0;
                #pragma unroll 4
                for (int q = 0; q < chunk; ++q) {
                    int s = __shfl(myid, q);
                    acc += __bfloat162float(hin[(long long)s * FEAT + f]);
                }
            }
            aggS[w][f]  = acc * deg_inv[n];
            selfS[w][f] = __bfloat162float(hin[(long long)n * FEAT + f]);
        }
        __syncthreads();
        if (act) {
            float o = bsh[f];
            #pragma unroll
            for (int k = 0; k < FEAT; ++k) {
                o = fmaf(aggS[w][k],  WlT[k * 65 + f], o);
                o = fmaf(selfS[w][k], WrT[k * 65 + f], o);
            }
            out[(long long)n * FEAT + f] = o;
        }
        __syncthreads();
    }
}

// ---------------------------------------------------------------------------
// Launch
// ---------------------------------------------------------------------------
extern "C" void kernel_launch(void* const* d_in, const int* in_sizes, int n_in,
                              void* d_out, int out_size, void* d_ws, size_t ws_size,
                              hipStream_t stream) {
    const float* x   = (const float*)d_in[0];
    const void*  ei  = d_in[1];
    const float* W1l = (const float*)d_in[2];
    const float* b1  = (const float*)d_in[3];
    const float* W1r = (const float*)d_in[4];
    const float* W2l = (const float*)d_in[5];
    const float* b2  = (const float*)d_in[6];
    const float* W2r = (const float*)d_in[7];
    float* out = (float*)d_out;

    const int n_nodes = in_sizes[0] / FEAT;
    const int n_edges = in_sizes[1] / 2;
    const int nparts  = (n_nodes + 255) / 256;     // <= 512 for n_nodes <= 131072

    // Workspace layout (256B-aligned), total ~20.8 MB
    char* ws = (char*)d_ws;
    size_t o = 0;
    auto al = [](size_t v) { return (v + 255) & ~(size_t)255; };
    int* flag    = (int*)(ws + o);            o += 256;
    int* degc    = (int*)(ws + o);            o += al((size_t)n_nodes * 4);
    float* dinv  = (float*)(ws + o);          o += al((size_t)n_nodes * 4);
    int* offs    = (int*)(ws + o);            o += al((size_t)n_nodes * 4);
    int* cursor  = (int*)(ws + o);            o += al((size_t)n_nodes * 4);
    int* part    = (int*)(ws + o);            o += al(512 * 4);
    int* csr     = (int*)(ws + o);            o += al((size_t)n_edges * 4);
    __hip_bfloat16* h = (__hip_bfloat16*)(ws + o);

    zero2_kernel<<<nparts, 256, 0, stream>>>(degc, cursor, n_nodes);
    detect_idx_kernel<<<1, 256, 0, stream>>>((const unsigned*)ei, flag);

    const int egrid = (n_edges + 255) / 256;
    hist_kernel<<<egrid, 256, 0, stream>>>(ei, flag, degc, n_edges, n_nodes);
    scan_partial_kernel<<<nparts, 256, 0, stream>>>(degc, part, n_nodes);
    scan_top_kernel<<<1, 512, 0, stream>>>(part, nparts);
    scan_final_kernel<<<nparts, 256, 0, stream>>>(degc, part, offs, dinv, n_nodes);
    csr_scatter_kernel<<<egrid, 256, 0, stream>>>(ei, flag, offs, cursor, csr, n_edges, n_nodes);

    const int n_groups = (n_nodes + 3) / 4;
    const int fgrid = n_groups < 4096 ? n_groups : 4096;
    sage_fused_l1_kernel<<<fgrid, 256, 0, stream>>>(x, offs, degc, dinv, csr,
                                                    W1l, b1, W1r, h, n_nodes);
    sage_fused_l2_kernel<<<fgrid, 256, 0, stream>>>(h, offs, degc, dinv, csr,
                                                    W2l, b2, W2r, out, n_nodes);
}

// Round 4
// 403.826 us; speedup vs baseline: 2.7300x; 1.8040x over previous
//
#include <hip/hip_runtime.h>
#include <hip/hip_bf16.h>

#define FEAT 64

typedef __bf16 bf16x8 __attribute__((ext_vector_type(8)));
typedef __bf16 bf16x4 __attribute__((ext_vector_type(4)));
typedef float  f32x4  __attribute__((ext_vector_type(4)));

// ---------------------------------------------------------------------------
// Zero int buffers via kernel (hipMemsetAsync may run at capture time, not as
// a graph node -> poisoned on replay; learned in R2).
// ---------------------------------------------------------------------------
__global__ __launch_bounds__(256)
void zero2_kernel(int* __restrict__ a, int* __restrict__ b, int n) {
    int i = blockIdx.x * 256 + threadIdx.x;
    if (i < n) { a[i] = 0; b[i] = 0; }
}

// ---------------------------------------------------------------------------
// int64-vs-int32 edge_index sniffer (flag=1 if int64).
// ---------------------------------------------------------------------------
__global__ void detect_idx_kernel(const unsigned* __restrict__ w, int* __restrict__ flag) {
    __shared__ int any_nz;
    if (threadIdx.x == 0) any_nz = 0;
    __syncthreads();
    if (w[2 * threadIdx.x + 1] != 0u) atomicOr(&any_nz, 1);  // first 2KB only
    __syncthreads();
    if (threadIdx.x == 0) *flag = (any_nz == 0) ? 1 : 0;
}

__device__ __forceinline__ int load_idx_clamped(const void* ei, long long i, int is64, int n_nodes) {
    int v = is64 ? (int)((const long long*)ei)[i] : ((const int*)ei)[i];
    v = v < 0 ? 0 : v;
    return v >= n_nodes ? n_nodes - 1 : v;   // identity when data is sane
}

// ---------------------------------------------------------------------------
// CSR build: histogram -> block partials -> top scan -> final scan -> scatter
// ---------------------------------------------------------------------------
__global__ __launch_bounds__(256)
void hist_kernel(const void* __restrict__ ei, const int* __restrict__ flagp,
                 int* __restrict__ degc, int n_edges, int n_nodes) {
    int e = blockIdx.x * 256 + threadIdx.x;
    if (e >= n_edges) return;
    int d = load_idx_clamped(ei, (long long)n_edges + e, *flagp, n_nodes);
    atomicAdd(&degc[d], 1);
}

__global__ __launch_bounds__(256)
void scan_partial_kernel(const int* __restrict__ degc, int* __restrict__ part, int n_nodes) {
    __shared__ int sh[256];
    int i = blockIdx.x * 256 + threadIdx.x;
    sh[threadIdx.x] = (i < n_nodes) ? degc[i] : 0;
    __syncthreads();
    for (int off = 128; off > 0; off >>= 1) {
        if (threadIdx.x < off) sh[threadIdx.x] += sh[threadIdx.x + off];
        __syncthreads();
    }
    if (threadIdx.x == 0) part[blockIdx.x] = sh[0];
}

__global__ void scan_top_kernel(int* __restrict__ part, int nparts) {
    __shared__ int sh[512];
    int t = threadIdx.x;
    int v = (t < nparts) ? part[t] : 0;
    sh[t] = v;
    __syncthreads();
    for (int off = 1; off < 512; off <<= 1) {
        int u = (t >= off) ? sh[t - off] : 0;
        __syncthreads();
        sh[t] += u;
        __syncthreads();
    }
    if (t < nparts) part[t] = sh[t] - v;   // exclusive
}

__global__ __launch_bounds__(256)
void scan_final_kernel(const int* __restrict__ degc, const int* __restrict__ part,
                       int* __restrict__ offs, float* __restrict__ deg_inv, int n_nodes) {
    __shared__ int sh[256];
    int t = threadIdx.x;
    int i = blockIdx.x * 256 + t;
    int v = (i < n_nodes) ? degc[i] : 0;
    sh[t] = v;
    __syncthreads();
    for (int off = 1; off < 256; off <<= 1) {
        int u = (t >= off) ? sh[t - off] : 0;
        __syncthreads();
        sh[t] += u;
        __syncthreads();
    }
    if (i < n_nodes) {
        offs[i]    = sh[t] - v + part[blockIdx.x];
        deg_inv[i] = 1.0f / fmaxf((float)v, 1.0f);
    }
}

__global__ __launch_bounds__(256)
void csr_scatter_kernel(const void* __restrict__ ei, const int* __restrict__ flagp,
                        const int* __restrict__ offs, int* __restrict__ cursor,
                        int* __restrict__ csr, int n_edges, int n_nodes) {
    int e = blockIdx.x * 256 + threadIdx.x;
    if (e >= n_edges) return;
    int is64 = *flagp;
    int s = load_idx_clamped(ei, e, is64, n_nodes);
    int d = load_idx_clamped(ei, (long long)n_edges + e, is64, n_nodes);
    int pos = offs[d] + atomicAdd(&cursor[d], 1);
    pos = pos < 0 ? 0 : (pos >= n_edges ? n_edges - 1 : pos);
    csr[pos] = s;
}

// ---------------------------------------------------------------------------
// Weight cast: four 64x64 f32 matrices -> one packed bf16 buffer.
// ---------------------------------------------------------------------------
__global__ __launch_bounds__(256)
void cast_w_kernel(const float* __restrict__ a, const float* __restrict__ b,
                   const float* __restrict__ c, const float* __restrict__ d,
                   __bf16* __restrict__ o) {
    int i = blockIdx.x * 256 + threadIdx.x;
    if (i < FEAT * FEAT) {
        o[i]            = (__bf16)a[i];
        o[4096 + i]     = (__bf16)b[i];
        o[8192 + i]     = (__bf16)c[i];
        o[12288 + i]    = (__bf16)d[i];
    }
}

// ---------------------------------------------------------------------------
// Pure gather kernels: wave per node, NO LDS. Lanes form 4 groups of 16;
// group g loads 16B of neighbor (q+g)'s row -> 4 independent chains, 4x fewer
// load instructions. Butterfly xor-16/32 merges groups; group 0 stores the
// mean row as bf16x4 (8B/lane, 128B coalesced).
// ---------------------------------------------------------------------------
__global__ __launch_bounds__(256)
void gather_f32_kernel(const float* __restrict__ xin, const int* __restrict__ offs,
                       const int* __restrict__ degc, const float* __restrict__ dinv,
                       const int* __restrict__ csr, __bf16* __restrict__ agg,
                       int n_nodes) {
    const int t = threadIdx.x, lane = t & 63, g = lane >> 4, u = lane & 15;
    const int gw = blockIdx.x * 4 + (t >> 6), nw = gridDim.x * 4;
    for (int n = gw; n < n_nodes; n += nw) {
        int rs = offs[n], cnt = degc[n];
        float a0 = 0.f, a1 = 0.f, a2 = 0.f, a3 = 0.f;
        for (int c = 0; c < cnt; c += 64) {
            int chunk = min(64, cnt - c);
            int myid = (lane < chunk) ? csr[rs + c + lane] : 0;
            for (int q = 0; q < chunk; q += 4) {
                int qq = q + g;
                int s = __shfl(myid, qq);
                if (qq < chunk) {
                    const float4 v = ((const float4*)xin)[(size_t)s * 16 + u];
                    a0 += v.x; a1 += v.y; a2 += v.z; a3 += v.w;
                }
            }
        }
        a0 += __shfl_xor(a0, 16); a1 += __shfl_xor(a1, 16);
        a2 += __shfl_xor(a2, 16); a3 += __shfl_xor(a3, 16);
        a0 += __shfl_xor(a0, 32); a1 += __shfl_xor(a1, 32);
        a2 += __shfl_xor(a2, 32); a3 += __shfl_xor(a3, 32);
        if (g == 0) {
            float di = dinv[n];
            bf16x4 o;
            o.x = (__bf16)(a0 * di); o.y = (__bf16)(a1 * di);
            o.z = (__bf16)(a2 * di); o.w = (__bf16)(a3 * di);
            ((bf16x4*)agg)[(size_t)n * 16 + u] = o;
        }
    }
}

__global__ __launch_bounds__(256)
void gather_bf16_kernel(const __bf16* __restrict__ hin, const int* __restrict__ offs,
                        const int* __restrict__ degc, const float* __restrict__ dinv,
                        const int* __restrict__ csr, __bf16* __restrict__ agg,
                        int n_nodes) {
    const int t = threadIdx.x, lane = t & 63, g = lane >> 4, u = lane & 15;
    const int gw = blockIdx.x * 4 + (t >> 6), nw = gridDim.x * 4;
    for (int n = gw; n < n_nodes; n += nw) {
        int rs = offs[n], cnt = degc[n];
        float a0 = 0.f, a1 = 0.f, a2 = 0.f, a3 = 0.f;
        for (int c = 0; c < cnt; c += 64) {
            int chunk = min(64, cnt - c);
            int myid = (lane < chunk) ? csr[rs + c + lane] : 0;
            for (int q = 0; q < chunk; q += 4) {
                int qq = q + g;
                int s = __shfl(myid, qq);
                if (qq < chunk) {
                    const bf16x4 v = ((const bf16x4*)hin)[(size_t)s * 16 + u];
                    a0 += (float)v.x; a1 += (float)v.y; a2 += (float)v.z; a3 += (float)v.w;
                }
            }
        }
        a0 += __shfl_xor(a0, 16); a1 += __shfl_xor(a1, 16);
        a2 += __shfl_xor(a2, 16); a3 += __shfl_xor(a3, 16);
        a0 += __shfl_xor(a0, 32); a1 += __shfl_xor(a1, 32);
        a2 += __shfl_xor(a2, 32); a3 += __shfl_xor(a3, 32);
        if (g == 0) {
            float di = dinv[n];
            bf16x4 o;
            o.x = (__bf16)(a0 * di); o.y = (__bf16)(a1 * di);
            o.z = (__bf16)(a2 * di); o.w = (__bf16)(a3 * di);
            ((bf16x4*)agg)[(size_t)n * 16 + u] = o;
        }
    }
}

// ---------------------------------------------------------------------------
// MFMA GEMM, layer 1: h = relu(agg @ Wl^T + x @ Wr^T + b), bf16 out.
// Per wave: 16 nodes x 64 outputs = 4 C-tiles, 16 MFMAs (16x16x32 bf16).
// A frag: A[m=lane&15][k=quad*8+j]; B frag: B[k=quad*8+j][n=lane&15];
// C/D: col=lane&15, row=quad*4+reg (m89/m91/m120-verified layouts).
// ---------------------------------------------------------------------------
__global__ __launch_bounds__(256)
void gemm_l1_kernel(const __bf16* __restrict__ Ag, const float* __restrict__ xin,
                    const __bf16* __restrict__ Bl, const __bf16* __restrict__ Br,
                    const float* __restrict__ bias,
                    __bf16* __restrict__ hout, int n_nodes) {
    const int t = threadIdx.x, lane = t & 63;
    const int quad = lane >> 4, r16 = lane & 15;
    bf16x8 bl[2][4], br[2][4];
    #pragma unroll
    for (int ks = 0; ks < 2; ++ks)
        #pragma unroll
        for (int ct = 0; ct < 4; ++ct) {
            int f = ct * 16 + r16, k = ks * 32 + quad * 8;
            bl[ks][ct] = *(const bf16x8*)(Bl + f * 64 + k);
            br[ks][ct] = *(const bf16x8*)(Br + f * 64 + k);
        }
    const int m0 = (blockIdx.x * 4 + (t >> 6)) * 16;
    if (m0 >= n_nodes) return;
    int mrow = m0 + r16; if (mrow >= n_nodes) mrow = n_nodes - 1;
    bf16x8 ag[2], ax[2];
    #pragma unroll
    for (int ks = 0; ks < 2; ++ks) {
        ag[ks] = *(const bf16x8*)(Ag + (size_t)mrow * 64 + ks * 32 + quad * 8);
        const float* xr = xin + (size_t)mrow * 64 + ks * 32 + quad * 8;
        float4 p = *(const float4*)xr;
        float4 q = *(const float4*)(xr + 4);
        union { bf16x8 v; __bf16 e[8]; } U;
        U.e[0] = (__bf16)p.x; U.e[1] = (__bf16)p.y; U.e[2] = (__bf16)p.z; U.e[3] = (__bf16)p.w;
        U.e[4] = (__bf16)q.x; U.e[5] = (__bf16)q.y; U.e[6] = (__bf16)q.z; U.e[7] = (__bf16)q.w;
        ax[ks] = U.v;
    }
    #pragma unroll
    for (int ct = 0; ct < 4; ++ct) {
        f32x4 acc = {0.f, 0.f, 0.f, 0.f};
        acc = __builtin_amdgcn_mfma_f32_16x16x32_bf16(ag[0], bl[0][ct], acc, 0, 0, 0);
        acc = __builtin_amdgcn_mfma_f32_16x16x32_bf16(ag[1], bl[1][ct], acc, 0, 0, 0);
        acc = __builtin_amdgcn_mfma_f32_16x16x32_bf16(ax[0], br[0][ct], acc, 0, 0, 0);
        acc = __builtin_amdgcn_mfma_f32_16x16x32_bf16(ax[1], br[1][ct], acc, 0, 0, 0);
        int col = ct * 16 + r16;
        float bv = bias[col];
        #pragma unroll
        for (int rg = 0; rg < 4; ++rg) {
            int n = m0 + quad * 4 + rg;
            if (n < n_nodes) {
                float o = acc[rg] + bv;
                o = fmaxf(o, 0.f);
                hout[(size_t)n * 64 + col] = (__bf16)o;
            }
        }
    }
}

// Layer 2: out = agg2 @ W2l^T + h @ W2r^T + b2, f32 out, no relu.
__global__ __launch_bounds__(256)
void gemm_l2_kernel(const __bf16* __restrict__ Ag, const __bf16* __restrict__ Ah,
                    const __bf16* __restrict__ Bl, const __bf16* __restrict__ Br,
                    const float* __restrict__ bias,
                    float* __restrict__ out, int n_nodes) {
    const int t = threadIdx.x, lane = t & 63;
    const int quad = lane >> 4, r16 = lane & 15;
    bf16x8 bl[2][4], br[2][4];
    #pragma unroll
    for (int ks = 0; ks < 2; ++ks)
        #pragma unroll
        for (int ct = 0; ct < 4; ++ct) {
            int f = ct * 16 + r16, k = ks * 32 + quad * 8;
            bl[ks][ct] = *(const bf16x8*)(Bl + f * 64 + k);
            br[ks][ct] = *(const bf16x8*)(Br + f * 64 + k);
        }
    const int m0 = (blockIdx.x * 4 + (t >> 6)) * 16;
    if (m0 >= n_nodes) return;
    int mrow = m0 + r16; if (mrow >= n_nodes) mrow = n_nodes - 1;
    bf16x8 ag[2], ah[2];
    #pragma unroll
    for (int ks = 0; ks < 2; ++ks) {
        ag[ks] = *(const bf16x8*)(Ag + (size_t)mrow * 64 + ks * 32 + quad * 8);
        ah[ks] = *(const bf16x8*)(Ah + (size_t)mrow * 64 + ks * 32 + quad * 8);
    }
    #pragma unroll
    for (int ct = 0; ct < 4; ++ct) {
        f32x4 acc = {0.f, 0.f, 0.f, 0.f};
        acc = __builtin_amdgcn_mfma_f32_16x16x32_bf16(ag[0], bl[0][ct], acc, 0, 0, 0);
        acc = __builtin_amdgcn_mfma_f32_16x16x32_bf16(ag[1], bl[1][ct], acc, 0, 0, 0);
        acc = __builtin_amdgcn_mfma_f32_16x16x32_bf16(ah[0], br[0][ct], acc, 0, 0, 0);
        acc = __builtin_amdgcn_mfma_f32_16x16x32_bf16(ah[1], br[1][ct], acc, 0, 0, 0);
        int col = ct * 16 + r16;
        float bv = bias[col];
        #pragma unroll
        for (int rg = 0; rg < 4; ++rg) {
            int n = m0 + quad * 4 + rg;
            if (n < n_nodes) out[(size_t)n * 64 + col] = acc[rg] + bv;
        }
    }
}

// ---------------------------------------------------------------------------
// FALLBACK (ws too small): R3's proven fused kernels (LDS-bound but correct).
// ---------------------------------------------------------------------------
__global__ __launch_bounds__(256)
void sage_fused_l1_kernel(const float* __restrict__ xin,
                          const int* __restrict__ offs, const int* __restrict__ degc,
                          const float* __restrict__ deg_inv, const int* __restrict__ csr,
                          const float* __restrict__ Wl, const float* __restrict__ bias,
                          const float* __restrict__ Wr,
                          __bf16* __restrict__ hout, int n_nodes) {
    __shared__ float WlT[FEAT * 65], WrT[FEAT * 65], bsh[FEAT];
    __shared__ float aggS[4][FEAT], selfS[4][FEAT];
    const int t = threadIdx.x;
    #pragma unroll
    for (int p = 0; p < 16; ++p) {
        int i = t + p * 256, j = i >> 6, k = i & 63;
        WlT[k * 65 + j] = Wl[i];
        WrT[k * 65 + j] = Wr[i];
    }
    if (t < FEAT) bsh[t] = bias[t];
    __syncthreads();
    const int w = t >> 6, f = t & 63;
    const int n_groups = (n_nodes + 3) >> 2;
    for (int g = blockIdx.x; g < n_groups; g += gridDim.x) {
        int n = g * 4 + w;
        bool act = (n < n_nodes);
        if (act) {
            int rs = offs[n], cnt = degc[n];
            float acc = 0.f;
            for (int c = 0; c < cnt; c += 64) {
                int chunk = min(64, cnt - c);
                int myid = (f < chunk) ? csr[rs + c + f] : 0;
                #pragma unroll 4
                for (int q = 0; q < chunk; ++q) {
                    int s = __shfl(myid, q);
                    acc += xin[(long long)s * FEAT + f];
                }
            }
            aggS[w][f]  = acc * deg_inv[n];
            selfS[w][f] = xin[(long long)n * FEAT + f];
        }
        __syncthreads();
        if (act) {
            float o = bsh[f];
            #pragma unroll
            for (int k = 0; k < FEAT; ++k) {
                o = fmaf(aggS[w][k],  WlT[k * 65 + f], o);
                o = fmaf(selfS[w][k], WrT[k * 65 + f], o);
            }
            o = fmaxf(o, 0.f);
            hout[(long long)n * FEAT + f] = (__bf16)o;
        }
        __syncthreads();
    }
}

__global__ __launch_bounds__(256)
void sage_fused_l2_kernel(const __bf16* __restrict__ hin,
                          const int* __restrict__ offs, const int* __restrict__ degc,
                          const float* __restrict__ deg_inv, const int* __restrict__ csr,
                          const float* __restrict__ Wl, const float* __restrict__ bias,
                          const float* __restrict__ Wr,
                          float* __restrict__ out, int n_nodes) {
    __shared__ float WlT[FEAT * 65], WrT[FEAT * 65], bsh[FEAT];
    __shared__ float aggS[4][FEAT], selfS[4][FEAT];
    const int t = threadIdx.x;
    #pragma unroll
    for (int p = 0; p < 16; ++p) {
        int i = t + p * 256, j = i >> 6, k = i & 63;
        WlT[k * 65 + j] = Wl[i];
        WrT[k * 65 + j] = Wr[i];
    }
    if (t < FEAT) bsh[t] = bias[t];
    __syncthreads();
    const int w = t >> 6, f = t & 63;
    const int n_groups = (n_nodes + 3) >> 2;
    for (int g = blockIdx.x; g < n_groups; g += gridDim.x) {
        int n = g * 4 + w;
        bool act = (n < n_nodes);
        if (act) {
            int rs = offs[n], cnt = degc[n];
            float acc = 0.f;
            for (int c = 0; c < cnt; c += 64) {
                int chunk = min(64, cnt - c);
                int myid = (f < chunk) ? csr[rs + c + f] : 0;
                #pragma unroll 4
                for (int q = 0; q < chunk; ++q) {
                    int s = __shfl(myid, q);
                    acc += (float)hin[(long long)s * FEAT + f];
                }
            }
            aggS[w][f]  = acc * deg_inv[n];
            selfS[w][f] = (float)hin[(long long)n * FEAT + f];
        }
        __syncthreads();
        if (act) {
            float o = bsh[f];
            #pragma unroll
            for (int k = 0; k < FEAT; ++k) {
                o = fmaf(aggS[w][k],  WlT[k * 65 + f], o);
                o = fmaf(selfS[w][k], WrT[k * 65 + f], o);
            }
            out[(long long)n * FEAT + f] = o;
        }
        __syncthreads();
    }
}

// ---------------------------------------------------------------------------
// Launch
// ---------------------------------------------------------------------------
extern "C" void kernel_launch(void* const* d_in, const int* in_sizes, int n_in,
                              void* d_out, int out_size, void* d_ws, size_t ws_size,
                              hipStream_t stream) {
    const float* x   = (const float*)d_in[0];
    const void*  ei  = d_in[1];
    const float* W1l = (const float*)d_in[2];
    const float* b1  = (const float*)d_in[3];
    const float* W1r = (const float*)d_in[4];
    const float* W2l = (const float*)d_in[5];
    const float* b2  = (const float*)d_in[6];
    const float* W2r = (const float*)d_in[7];
    float* out = (float*)d_out;

    const int n_nodes = in_sizes[0] / FEAT;
    const int n_edges = in_sizes[1] / 2;
    const int nparts  = (n_nodes + 255) / 256;     // <= 512

    char* ws = (char*)d_ws;
    size_t o = 0;
    auto al = [](size_t v) { return (v + 255) & ~(size_t)255; };
    int* flag    = (int*)(ws + o);            o += 256;
    int* degc    = (int*)(ws + o);            o += al((size_t)n_nodes * 4);
    float* dinv  = (float*)(ws + o);          o += al((size_t)n_nodes * 4);
    int* offs    = (int*)(ws + o);            o += al((size_t)n_nodes * 4);
    int* cursor  = (int*)(ws + o);            o += al((size_t)n_nodes * 4);
    int* part    = (int*)(ws + o);            o += al(2048);
    int* csr     = (int*)(ws + o);            o += al((size_t)n_edges * 4);
    const size_t commonEnd = o;

    // big-path extras
    const size_t wbB  = al((size_t)4 * FEAT * FEAT * 2);
    const size_t rowB = al((size_t)n_nodes * FEAT * 2);
    const size_t bigNeed = commonEnd + wbB + 2 * rowB;
    const bool big = (ws_size >= bigNeed);

    zero2_kernel<<<nparts, 256, 0, stream>>>(degc, cursor, n_nodes);
    detect_idx_kernel<<<1, 256, 0, stream>>>((const unsigned*)ei, flag);

    const int egrid = (n_edges + 255) / 256;
    hist_kernel<<<egrid, 256, 0, stream>>>(ei, flag, degc, n_edges, n_nodes);
    scan_partial_kernel<<<nparts, 256, 0, stream>>>(degc, part, n_nodes);
    scan_top_kernel<<<1, 512, 0, stream>>>(part, nparts);
    scan_final_kernel<<<nparts, 256, 0, stream>>>(degc, part, offs, dinv, n_nodes);
    csr_scatter_kernel<<<egrid, 256, 0, stream>>>(ei, flag, offs, cursor, csr, n_edges, n_nodes);

    if (big) {
        __bf16* wb  = (__bf16*)(ws + commonEnd);
        __bf16* agg = (__bf16*)(ws + commonEnd + wbB);
        __bf16* h   = (__bf16*)(ws + commonEnd + wbB + rowB);

        cast_w_kernel<<<16, 256, 0, stream>>>(W1l, W1r, W2l, W2r, wb);

        const int ggrid = 2048;                          // 8192 waves, no LDS
        const int mgrid = (n_nodes + 63) / 64;           // 4 waves x 16 nodes / block
        gather_f32_kernel<<<ggrid, 256, 0, stream>>>(x, offs, degc, dinv, csr, agg, n_nodes);
        gemm_l1_kernel<<<mgrid, 256, 0, stream>>>(agg, x, wb, wb + 4096, b1, h, n_nodes);
        gather_bf16_kernel<<<ggrid, 256, 0, stream>>>(h, offs, degc, dinv, csr, agg, n_nodes);
        gemm_l2_kernel<<<mgrid, 256, 0, stream>>>(agg, h, wb + 8192, wb + 12288, b2, out, n_nodes);
    } else {
        __bf16* h = (__bf16*)(ws + commonEnd);
        const int n_groups = (n_nodes + 3) / 4;
        const int fgrid = n_groups < 4096 ? n_groups : 4096;
        sage_fused_l1_kernel<<<fgrid, 256, 0, stream>>>(x, offs, degc, dinv, csr,
                                                        W1l, b1, W1r, h, n_nodes);
        sage_fused_l2_kernel<<<fgrid, 256, 0, stream>>>(h, offs, degc, dinv, csr,
                                                        W2l, b2, W2r, out, n_nodes);
    }
}

// Round 5
// 351.526 us; speedup vs baseline: 3.1362x; 1.1488x over previous
//
#include <hip/hip_runtime.h>
#include <hip/hip_bf16.h>

#define FEAT 64

typedef __bf16 bf16x8 __attribute__((ext_vector_type(8)));
typedef __bf16 bf16x4 __attribute__((ext_vector_type(4)));
typedef float  f32x4  __attribute__((ext_vector_type(4)));

// ---------------------------------------------------------------------------
// Zero int buffers via kernel (hipMemsetAsync may run at capture time, not as
// a graph node -> poisoned on replay; learned in R2).
// ---------------------------------------------------------------------------
__global__ __launch_bounds__(256)
void zero1_kernel(int* __restrict__ a, int n) {
    int i = blockIdx.x * 256 + threadIdx.x;
    if (i < n) a[i] = 0;
}

__global__ __launch_bounds__(256)
void zero2_kernel(int* __restrict__ a, int* __restrict__ b, int n) {
    int i = blockIdx.x * 256 + threadIdx.x;
    if (i < n) { a[i] = 0; b[i] = 0; }
}

// ---------------------------------------------------------------------------
// int64-vs-int32 edge_index sniffer (flag=1 if int64).
// ---------------------------------------------------------------------------
__global__ void detect_idx_kernel(const unsigned* __restrict__ w, int* __restrict__ flag) {
    __shared__ int any_nz;
    if (threadIdx.x == 0) any_nz = 0;
    __syncthreads();
    if (w[2 * threadIdx.x + 1] != 0u) atomicOr(&any_nz, 1);  // first 2KB only
    __syncthreads();
    if (threadIdx.x == 0) *flag = (any_nz == 0) ? 1 : 0;
}

__device__ __forceinline__ int load_idx_clamped(const void* ei, long long i, int is64, int n_nodes) {
    int v = is64 ? (int)((const long long*)ei)[i] : ((const int*)ei)[i];
    v = v < 0 ? 0 : v;
    return v >= n_nodes ? n_nodes - 1 : v;   // identity when data is sane
}

// ---------------------------------------------------------------------------
// T1 path: hist + decode + rank. dr[e] = (d<<15) | min(rank,32767).
// d < 2^17 (n_nodes <= 131071), rank < 32768 (max degree bound; clamped so a
// violation stays in-bounds, never OOB).
// ---------------------------------------------------------------------------
__global__ __launch_bounds__(256)
void hist_decode_kernel(const void* __restrict__ ei, const int* __restrict__ flagp,
                        int* __restrict__ degc, unsigned* __restrict__ dr,
                        int n_edges, int n_nodes) {
    int e = blockIdx.x * 256 + threadIdx.x;
    if (e >= n_edges) return;
    int d = load_idx_clamped(ei, (long long)n_edges + e, *flagp, n_nodes);
    int r = atomicAdd(&degc[d], 1);
    if (r > 32767) r = 32767;
    dr[e] = ((unsigned)d << 15) | (unsigned)r;
}

// ---------------------------------------------------------------------------
// Scans (shared by all paths)
// ---------------------------------------------------------------------------
__global__ __launch_bounds__(256)
void scan_partial_kernel(const int* __restrict__ degc, int* __restrict__ part, int n_nodes) {
    __shared__ int sh[256];
    int i = blockIdx.x * 256 + threadIdx.x;
    sh[threadIdx.x] = (i < n_nodes) ? degc[i] : 0;
    __syncthreads();
    for (int off = 128; off > 0; off >>= 1) {
        if (threadIdx.x < off) sh[threadIdx.x] += sh[threadIdx.x + off];
        __syncthreads();
    }
    if (threadIdx.x == 0) part[blockIdx.x] = sh[0];
}

__global__ void scan_top_kernel(int* __restrict__ part, int nparts) {
    __shared__ int sh[512];
    int t = threadIdx.x;
    int v = (t < nparts) ? part[t] : 0;
    sh[t] = v;
    __syncthreads();
    for (int off = 1; off < 512; off <<= 1) {
        int u = (t >= off) ? sh[t - off] : 0;
        __syncthreads();
        sh[t] += u;
        __syncthreads();
    }
    if (t < nparts) part[t] = sh[t] - v;   // exclusive
}

__global__ __launch_bounds__(256)
void scan_final_kernel(const int* __restrict__ degc, const int* __restrict__ part,
                       int* __restrict__ offs, float* __restrict__ deg_inv, int n_nodes) {
    __shared__ int sh[256];
    int t = threadIdx.x;
    int i = blockIdx.x * 256 + t;
    int v = (i < n_nodes) ? degc[i] : 0;
    sh[t] = v;
    __syncthreads();
    for (int off = 1; off < 256; off <<= 1) {
        int u = (t >= off) ? sh[t - off] : 0;
        __syncthreads();
        sh[t] += u;
        __syncthreads();
    }
    if (i < n_nodes) {
        offs[i]    = sh[t] - v + part[blockIdx.x];
        deg_inv[i] = 1.0f / fmaxf((float)v, 1.0f);
    }
}

// ---------------------------------------------------------------------------
// T1 scatter: atomic-free, XCD-sliced for write merging. Block (c,j=blk&7)
// scans chunk c, writes only dst-slice j -> all stores to a csr line come from
// one XCD; nt loads keep streaming reads from evicting the write lines.
// ---------------------------------------------------------------------------
__global__ __launch_bounds__(256)
void scatter_xcd_kernel(const void* __restrict__ ei, const int* __restrict__ flagp,
                        const unsigned* __restrict__ dr, const int* __restrict__ offs,
                        int* __restrict__ csr, int n_edges, int n_nodes) {
    const int j = blockIdx.x & 7;
    const int slice = (n_nodes + 7) >> 3;
    const int lo = j * slice, hi = min(n_nodes, lo + slice);
    const int is64 = *flagp;
    const int nchunks = (n_edges + 255) >> 8, step = gridDim.x >> 3;
    for (int c = blockIdx.x >> 3; c < nchunks; c += step) {
        int e = c * 256 + threadIdx.x;
        if (e >= n_edges) continue;
        unsigned v = __builtin_nontemporal_load(&dr[e]);
        int d = (int)(v >> 15);
        if (d >= lo && d < hi) {
            int r = (int)(v & 32767u);
            int s = is64 ? (int)__builtin_nontemporal_load(&((const int*)ei)[2 * e])
                         : (int)__builtin_nontemporal_load(&((const int*)ei)[e]);
            s = s < 0 ? 0 : (s >= n_nodes ? n_nodes - 1 : s);
            int pos = offs[d] + r;
            pos = pos < 0 ? 0 : (pos >= n_edges ? n_edges - 1 : pos);
            csr[pos] = s;
        }
    }
}

// ---------------------------------------------------------------------------
// T3 path scatter (R4, proven): cursor atomics.
// ---------------------------------------------------------------------------
__global__ __launch_bounds__(256)
void hist_kernel(const void* __restrict__ ei, const int* __restrict__ flagp,
                 int* __restrict__ degc, int n_edges, int n_nodes) {
    int e = blockIdx.x * 256 + threadIdx.x;
    if (e >= n_edges) return;
    int d = load_idx_clamped(ei, (long long)n_edges + e, *flagp, n_nodes);
    atomicAdd(&degc[d], 1);
}

__global__ __launch_bounds__(256)
void csr_scatter_kernel(const void* __restrict__ ei, const int* __restrict__ flagp,
                        const int* __restrict__ offs, int* __restrict__ cursor,
                        int* __restrict__ csr, int n_edges, int n_nodes) {
    int e = blockIdx.x * 256 + threadIdx.x;
    if (e >= n_edges) return;
    int is64 = *flagp;
    int s = load_idx_clamped(ei, e, is64, n_nodes);
    int d = load_idx_clamped(ei, (long long)n_edges + e, is64, n_nodes);
    int pos = offs[d] + atomicAdd(&cursor[d], 1);
    pos = pos < 0 ? 0 : (pos >= n_edges ? n_edges - 1 : pos);
    csr[pos] = s;
}

// ---------------------------------------------------------------------------
// Casts
// ---------------------------------------------------------------------------
__global__ __launch_bounds__(256)
void cast_w_kernel(const float* __restrict__ a, const float* __restrict__ b,
                   const float* __restrict__ c, const float* __restrict__ d,
                   __bf16* __restrict__ o) {
    int i = blockIdx.x * 256 + threadIdx.x;
    if (i < FEAT * FEAT) {
        o[i]         = (__bf16)a[i];
        o[4096 + i]  = (__bf16)b[i];
        o[8192 + i]  = (__bf16)c[i];
        o[12288 + i] = (__bf16)d[i];
    }
}

__global__ __launch_bounds__(256)
void cast_x_kernel(const float* __restrict__ x, __bf16* __restrict__ xb, int n4) {
    int i = blockIdx.x * 256 + threadIdx.x;
    if (i < n4) {
        float4 v = ((const float4*)x)[i];
        bf16x4 o;
        o.x = (__bf16)v.x; o.y = (__bf16)v.y; o.z = (__bf16)v.z; o.w = (__bf16)v.w;
        ((bf16x4*)xb)[i] = o;
    }
}

// ---------------------------------------------------------------------------
// Gather kernels: wave per node, no LDS; 4 groups of 16 lanes = 4 independent
// chains; butterfly merge; group 0 stores mean row bf16x4.
// ---------------------------------------------------------------------------
__global__ __launch_bounds__(256)
void gather_f32_kernel(const float* __restrict__ xin, const int* __restrict__ offs,
                       const int* __restrict__ degc, const float* __restrict__ dinv,
                       const int* __restrict__ csr, __bf16* __restrict__ agg,
                       int n_nodes) {
    const int t = threadIdx.x, lane = t & 63, g = lane >> 4, u = lane & 15;
    const int gw = blockIdx.x * 4 + (t >> 6), nw = gridDim.x * 4;
    for (int n = gw; n < n_nodes; n += nw) {
        int rs = offs[n], cnt = degc[n];
        float a0 = 0.f, a1 = 0.f, a2 = 0.f, a3 = 0.f;
        for (int c = 0; c < cnt; c += 64) {
            int chunk = min(64, cnt - c);
            int myid = (lane < chunk) ? csr[rs + c + lane] : 0;
            myid = myid < 0 ? 0 : (myid >= n_nodes ? n_nodes - 1 : myid);
            for (int q = 0; q < chunk; q += 4) {
                int qq = q + g;
                int s = __shfl(myid, qq);
                if (qq < chunk) {
                    const float4 v = ((const float4*)xin)[(size_t)s * 16 + u];
                    a0 += v.x; a1 += v.y; a2 += v.z; a3 += v.w;
                }
            }
        }
        a0 += __shfl_xor(a0, 16); a1 += __shfl_xor(a1, 16);
        a2 += __shfl_xor(a2, 16); a3 += __shfl_xor(a3, 16);
        a0 += __shfl_xor(a0, 32); a1 += __shfl_xor(a1, 32);
        a2 += __shfl_xor(a2, 32); a3 += __shfl_xor(a3, 32);
        if (g == 0) {
            float di = dinv[n];
            bf16x4 o;
            o.x = (__bf16)(a0 * di); o.y = (__bf16)(a1 * di);
            o.z = (__bf16)(a2 * di); o.w = (__bf16)(a3 * di);
            ((bf16x4*)agg)[(size_t)n * 16 + u] = o;
        }
    }
}

__global__ __launch_bounds__(256)
void gather_bf16_kernel(const __bf16* __restrict__ hin, const int* __restrict__ offs,
                        const int* __restrict__ degc, const float* __restrict__ dinv,
                        const int* __restrict__ csr, __bf16* __restrict__ agg,
                        int n_nodes) {
    const int t = threadIdx.x, lane = t & 63, g = lane >> 4, u = lane & 15;
    const int gw = blockIdx.x * 4 + (t >> 6), nw = gridDim.x * 4;
    for (int n = gw; n < n_nodes; n += nw) {
        int rs = offs[n], cnt = degc[n];
        float a0 = 0.f, a1 = 0.f, a2 = 0.f, a3 = 0.f;
        for (int c = 0; c < cnt; c += 64) {
            int chunk = min(64, cnt - c);
            int myid = (lane < chunk) ? csr[rs + c + lane] : 0;
            myid = myid < 0 ? 0 : (myid >= n_nodes ? n_nodes - 1 : myid);
            for (int q = 0; q < chunk; q += 4) {
                int qq = q + g;
                int s = __shfl(myid, qq);
                if (qq < chunk) {
                    const bf16x4 v = ((const bf16x4*)hin)[(size_t)s * 16 + u];
                    a0 += (float)v.x; a1 += (float)v.y; a2 += (float)v.z; a3 += (float)v.w;
                }
            }
        }
        a0 += __shfl_xor(a0, 16); a1 += __shfl_xor(a1, 16);
        a2 += __shfl_xor(a2, 16); a3 += __shfl_xor(a3, 16);
        a0 += __shfl_xor(a0, 32); a1 += __shfl_xor(a1, 32);
        a2 += __shfl_xor(a2, 32); a3 += __shfl_xor(a3, 32);
        if (g == 0) {
            float di = dinv[n];
            bf16x4 o;
            o.x = (__bf16)(a0 * di); o.y = (__bf16)(a1 * di);
            o.z = (__bf16)(a2 * di); o.w = (__bf16)(a3 * di);
            ((bf16x4*)agg)[(size_t)n * 16 + u] = o;
        }
    }
}

// ---------------------------------------------------------------------------
// MFMA GEMMs (16x16x32 bf16; verified fragment layouts).
// gemm_l1b: self term from bf16 xb (T1).  gemm_l1: self term from f32 x (T3).
// ---------------------------------------------------------------------------
__global__ __launch_bounds__(256)
void gemm_l1b_kernel(const __bf16* __restrict__ Ag, const __bf16* __restrict__ xb,
                     const __bf16* __restrict__ Bl, const __bf16* __restrict__ Br,
                     const float* __restrict__ bias,
                     __bf16* __restrict__ hout, int n_nodes) {
    const int t = threadIdx.x, lane = t & 63;
    const int quad = lane >> 4, r16 = lane & 15;
    bf16x8 bl[2][4], br[2][4];
    #pragma unroll
    for (int ks = 0; ks < 2; ++ks)
        #pragma unroll
        for (int ct = 0; ct < 4; ++ct) {
            int f = ct * 16 + r16, k = ks * 32 + quad * 8;
            bl[ks][ct] = *(const bf16x8*)(Bl + f * 64 + k);
            br[ks][ct] = *(const bf16x8*)(Br + f * 64 + k);
        }
    const int m0 = (blockIdx.x * 4 + (t >> 6)) * 16;
    if (m0 >= n_nodes) return;
    int mrow = m0 + r16; if (mrow >= n_nodes) mrow = n_nodes - 1;
    bf16x8 ag[2], ax[2];
    #pragma unroll
    for (int ks = 0; ks < 2; ++ks) {
        ag[ks] = *(const bf16x8*)(Ag + (size_t)mrow * 64 + ks * 32 + quad * 8);
        ax[ks] = *(const bf16x8*)(xb + (size_t)mrow * 64 + ks * 32 + quad * 8);
    }
    #pragma unroll
    for (int ct = 0; ct < 4; ++ct) {
        f32x4 acc = {0.f, 0.f, 0.f, 0.f};
        acc = __builtin_amdgcn_mfma_f32_16x16x32_bf16(ag[0], bl[0][ct], acc, 0, 0, 0);
        acc = __builtin_amdgcn_mfma_f32_16x16x32_bf16(ag[1], bl[1][ct], acc, 0, 0, 0);
        acc = __builtin_amdgcn_mfma_f32_16x16x32_bf16(ax[0], br[0][ct], acc, 0, 0, 0);
        acc = __builtin_amdgcn_mfma_f32_16x16x32_bf16(ax[1], br[1][ct], acc, 0, 0, 0);
        int col = ct * 16 + r16;
        float bv = bias[col];
        #pragma unroll
        for (int rg = 0; rg < 4; ++rg) {
            int n = m0 + quad * 4 + rg;
            if (n < n_nodes) {
                float o = acc[rg] + bv;
                hout[(size_t)n * 64 + col] = (__bf16)fmaxf(o, 0.f);
            }
        }
    }
}

__global__ __launch_bounds__(256)
void gemm_l1_kernel(const __bf16* __restrict__ Ag, const float* __restrict__ xin,
                    const __bf16* __restrict__ Bl, const __bf16* __restrict__ Br,
                    const float* __restrict__ bias,
                    __bf16* __restrict__ hout, int n_nodes) {
    const int t = threadIdx.x, lane = t & 63;
    const int quad = lane >> 4, r16 = lane & 15;
    bf16x8 bl[2][4], br[2][4];
    #pragma unroll
    for (int ks = 0; ks < 2; ++ks)
        #pragma unroll
        for (int ct = 0; ct < 4; ++ct) {
            int f = ct * 16 + r16, k = ks * 32 + quad * 8;
            bl[ks][ct] = *(const bf16x8*)(Bl + f * 64 + k);
            br[ks][ct] = *(const bf16x8*)(Br + f * 64 + k);
        }
    const int m0 = (blockIdx.x * 4 + (t >> 6)) * 16;
    if (m0 >= n_nodes) return;
    int mrow = m0 + r16; if (mrow >= n_nodes) mrow = n_nodes - 1;
    bf16x8 ag[2], ax[2];
    #pragma unroll
    for (int ks = 0; ks < 2; ++ks) {
        ag[ks] = *(const bf16x8*)(Ag + (size_t)mrow * 64 + ks * 32 + quad * 8);
        const float* xr = xin + (size_t)mrow * 64 + ks * 32 + quad * 8;
        float4 p = *(const float4*)xr;
        float4 q = *(const float4*)(xr + 4);
        union { bf16x8 v; __bf16 e[8]; } U;
        U.e[0] = (__bf16)p.x; U.e[1] = (__bf16)p.y; U.e[2] = (__bf16)p.z; U.e[3] = (__bf16)p.w;
        U.e[4] = (__bf16)q.x; U.e[5] = (__bf16)q.y; U.e[6] = (__bf16)q.z; U.e[7] = (__bf16)q.w;
        ax[ks] = U.v;
    }
    #pragma unroll
    for (int ct = 0; ct < 4; ++ct) {
        f32x4 acc = {0.f, 0.f, 0.f, 0.f};
        acc = __builtin_amdgcn_mfma_f32_16x16x32_bf16(ag[0], bl[0][ct], acc, 0, 0, 0);
        acc = __builtin_amdgcn_mfma_f32_16x16x32_bf16(ag[1], bl[1][ct], acc, 0, 0, 0);
        acc = __builtin_amdgcn_mfma_f32_16x16x32_bf16(ax[0], br[0][ct], acc, 0, 0, 0);
        acc = __builtin_amdgcn_mfma_f32_16x16x32_bf16(ax[1], br[1][ct], acc, 0, 0, 0);
        int col = ct * 16 + r16;
        float bv = bias[col];
        #pragma unroll
        for (int rg = 0; rg < 4; ++rg) {
            int n = m0 + quad * 4 + rg;
            if (n < n_nodes) {
                float o = acc[rg] + bv;
                hout[(size_t)n * 64 + col] = (__bf16)fmaxf(o, 0.f);
            }
        }
    }
}

__global__ __launch_bounds__(256)
void gemm_l2_kernel(const __bf16* __restrict__ Ag, const __bf16* __restrict__ Ah,
                    const __bf16* __restrict__ Bl, const __bf16* __restrict__ Br,
                    const float* __restrict__ bias,
                    float* __restrict__ out, int n_nodes) {
    const int t = threadIdx.x, lane = t & 63;
    const int quad = lane >> 4, r16 = lane & 15;
    bf16x8 bl[2][4], br[2][4];
    #pragma unroll
    for (int ks = 0; ks < 2; ++ks)
        #pragma unroll
        for (int ct = 0; ct < 4; ++ct) {
            int f = ct * 16 + r16, k = ks * 32 + quad * 8;
            bl[ks][ct] = *(const bf16x8*)(Bl + f * 64 + k);
            br[ks][ct] = *(const bf16x8*)(Br + f * 64 + k);
        }
    const int m0 = (blockIdx.x * 4 + (t >> 6)) * 16;
    if (m0 >= n_nodes) return;
    int mrow = m0 + r16; if (mrow >= n_nodes) mrow = n_nodes - 1;
    bf16x8 ag[2], ah[2];
    #pragma unroll
    for (int ks = 0; ks < 2; ++ks) {
        ag[ks] = *(const bf16x8*)(Ag + (size_t)mrow * 64 + ks * 32 + quad * 8);
        ah[ks] = *(const bf16x8*)(Ah + (size_t)mrow * 64 + ks * 32 + quad * 8);
    }
    #pragma unroll
    for (int ct = 0; ct < 4; ++ct) {
        f32x4 acc = {0.f, 0.f, 0.f, 0.f};
        acc = __builtin_amdgcn_mfma_f32_16x16x32_bf16(ag[0], bl[0][ct], acc, 0, 0, 0);
        acc = __builtin_amdgcn_mfma_f32_16x16x32_bf16(ag[1], bl[1][ct], acc, 0, 0, 0);
        acc = __builtin_amdgcn_mfma_f32_16x16x32_bf16(ah[0], br[0][ct], acc, 0, 0, 0);
        acc = __builtin_amdgcn_mfma_f32_16x16x32_bf16(ah[1], br[1][ct], acc, 0, 0, 0);
        int col = ct * 16 + r16;
        float bv = bias[col];
        #pragma unroll
        for (int rg = 0; rg < 4; ++rg) {
            int n = m0 + quad * 4 + rg;
            if (n < n_nodes) out[(size_t)n * 64 + col] = acc[rg] + bv;
        }
    }
}

// ---------------------------------------------------------------------------
// T4 fallback (R3): fused LDS kernels.
// ---------------------------------------------------------------------------
__global__ __launch_bounds__(256)
void sage_fused_l1_kernel(const float* __restrict__ xin,
                          const int* __restrict__ offs, const int* __restrict__ degc,
                          const float* __restrict__ deg_inv, const int* __restrict__ csr,
                          const float* __restrict__ Wl, const float* __restrict__ bias,
                          const float* __restrict__ Wr,
                          __bf16* __restrict__ hout, int n_nodes) {
    __shared__ float WlT[FEAT * 65], WrT[FEAT * 65], bsh[FEAT];
    __shared__ float aggS[4][FEAT], selfS[4][FEAT];
    const int t = threadIdx.x;
    #pragma unroll
    for (int p = 0; p < 16; ++p) {
        int i = t + p * 256, j = i >> 6, k = i & 63;
        WlT[k * 65 + j] = Wl[i];
        WrT[k * 65 + j] = Wr[i];
    }
    if (t < FEAT) bsh[t] = bias[t];
    __syncthreads();
    const int w = t >> 6, f = t & 63;
    const int n_groups = (n_nodes + 3) >> 2;
    for (int g = blockIdx.x; g < n_groups; g += gridDim.x) {
        int n = g * 4 + w;
        bool act = (n < n_nodes);
        if (act) {
            int rs = offs[n], cnt = degc[n];
            float acc = 0.f;
            for (int c = 0; c < cnt; c += 64) {
                int chunk = min(64, cnt - c);
                int myid = (f < chunk) ? csr[rs + c + f] : 0;
                #pragma unroll 4
                for (int q = 0; q < chunk; ++q) {
                    int s = __shfl(myid, q);
                    acc += xin[(long long)s * FEAT + f];
                }
            }
            aggS[w][f]  = acc * deg_inv[n];
            selfS[w][f] = xin[(long long)n * FEAT + f];
        }
        __syncthreads();
        if (act) {
            float o = bsh[f];
            #pragma unroll
            for (int k = 0; k < FEAT; ++k) {
                o = fmaf(aggS[w][k],  WlT[k * 65 + f], o);
                o = fmaf(selfS[w][k], WrT[k * 65 + f], o);
            }
            o = fmaxf(o, 0.f);
            hout[(long long)n * FEAT + f] = (__bf16)o;
        }
        __syncthreads();
    }
}

__global__ __launch_bounds__(256)
void sage_fused_l2_kernel(const __bf16* __restrict__ hin,
                          const int* __restrict__ offs, const int* __restrict__ degc,
                          const float* __restrict__ deg_inv, const int* __restrict__ csr,
                          const float* __restrict__ Wl, const float* __restrict__ bias,
                          const float* __restrict__ Wr,
                          float* __restrict__ out, int n_nodes) {
    __shared__ float WlT[FEAT * 65], WrT[FEAT * 65], bsh[FEAT];
    __shared__ float aggS[4][FEAT], selfS[4][FEAT];
    const int t = threadIdx.x;
    #pragma unroll
    for (int p = 0; p < 16; ++p) {
        int i = t + p * 256, j = i >> 6, k = i & 63;
        WlT[k * 65 + j] = Wl[i];
        WrT[k * 65 + j] = Wr[i];
    }
    if (t < FEAT) bsh[t] = bias[t];
    __syncthreads();
    const int w = t >> 6, f = t & 63;
    const int n_groups = (n_nodes + 3) >> 2;
    for (int g = blockIdx.x; g < n_groups; g += gridDim.x) {
        int n = g * 4 + w;
        bool act = (n < n_nodes);
        if (act) {
            int rs = offs[n], cnt = degc[n];
            float acc = 0.f;
            for (int c = 0; c < cnt; c += 64) {
                int chunk = min(64, cnt - c);
                int myid = (f < chunk) ? csr[rs + c + f] : 0;
                #pragma unroll 4
                for (int q = 0; q < chunk; ++q) {
                    int s = __shfl(myid, q);
                    acc += (float)hin[(long long)s * FEAT + f];
                }
            }
            aggS[w][f]  = acc * deg_inv[n];
            selfS[w][f] = (float)hin[(long long)n * FEAT + f];
        }
        __syncthreads();
        if (act) {
            float o = bsh[f];
            #pragma unroll
            for (int k = 0; k < FEAT; ++k) {
                o = fmaf(aggS[w][k],  WlT[k * 65 + f], o);
                o = fmaf(selfS[w][k], WrT[k * 65 + f], o);
            }
            out[(long long)n * FEAT + f] = o;
        }
        __syncthreads();
    }
}

// ---------------------------------------------------------------------------
// Launch
// ---------------------------------------------------------------------------
extern "C" void kernel_launch(void* const* d_in, const int* in_sizes, int n_in,
                              void* d_out, int out_size, void* d_ws, size_t ws_size,
                              hipStream_t stream) {
    const float* x   = (const float*)d_in[0];
    const void*  ei  = d_in[1];
    const float* W1l = (const float*)d_in[2];
    const float* b1  = (const float*)d_in[3];
    const float* W1r = (const float*)d_in[4];
    const float* W2l = (const float*)d_in[5];
    const float* b2  = (const float*)d_in[6];
    const float* W2r = (const float*)d_in[7];
    float* out = (float*)d_out;

    const int n_nodes = in_sizes[0] / FEAT;
    const int n_edges = in_sizes[1] / 2;
    const int nparts  = (n_nodes + 255) / 256;     // <= 512
    const int egrid   = (n_edges + 255) / 256;

    char* ws = (char*)d_ws;
    auto al = [](size_t v) { return (v + 255) & ~(size_t)255; };

    // ---- T1 layout (~52.4 MB) ----
    size_t o = 0;
    int*      flag = (int*)(ws + o);      o += 256;
    int*      degc = (int*)(ws + o);      o += al((size_t)n_nodes * 4);
    float*    dinv = (float*)(ws + o);    o += al((size_t)n_nodes * 4);
    int*      offs = (int*)(ws + o);      o += al((size_t)n_nodes * 4);
    int*      part = (int*)(ws + o);      o += al(2048);
    unsigned* dr   = (unsigned*)(ws + o); o += al((size_t)n_edges * 4);
    int*      csr  = (int*)(ws + o);      o += al((size_t)n_edges * 4);
    __bf16*   xb   = (__bf16*)(ws + o);   o += al((size_t)n_nodes * FEAT * 2);
    __bf16*   wb   = (__bf16*)(ws + o);   o += al((size_t)4 * FEAT * FEAT * 2);
    __bf16*   agg  = (__bf16*)(ws + o);   o += al((size_t)n_nodes * FEAT * 2);
    __bf16*   h    = (__bf16*)(ws + o);   o += al((size_t)n_nodes * FEAT * 2);
    const size_t needT1 = o;

    // ---- T3 layout (R4, ~33.6 MB) ----
    size_t o3 = 0;
    int*    flag3   = (int*)(ws + o3);    o3 += 256;
    int*    degc3   = (int*)(ws + o3);    o3 += al((size_t)n_nodes * 4);
    float*  dinv3   = (float*)(ws + o3);  o3 += al((size_t)n_nodes * 4);
    int*    offs3   = (int*)(ws + o3);    o3 += al((size_t)n_nodes * 4);
    int*    cursor3 = (int*)(ws + o3);    o3 += al((size_t)n_nodes * 4);
    int*    part3   = (int*)(ws + o3);    o3 += al(2048);
    int*    csr3    = (int*)(ws + o3);    o3 += al((size_t)n_edges * 4);
    const size_t commonEnd3 = o3;
    __bf16* wb3  = (__bf16*)(ws + o3);    o3 += al((size_t)4 * FEAT * FEAT * 2);
    __bf16* agg3 = (__bf16*)(ws + o3);    o3 += al((size_t)n_nodes * FEAT * 2);
    __bf16* h3   = (__bf16*)(ws + o3);    o3 += al((size_t)n_nodes * FEAT * 2);
    const size_t needT3 = o3;

    const int n4 = n_nodes * FEAT / 4;
    const int mgrid = (n_nodes + 63) / 64;
    const int ggrid = 2048;

    if (ws_size >= needT1) {
        zero1_kernel<<<nparts, 256, 0, stream>>>(degc, n_nodes);
        detect_idx_kernel<<<1, 256, 0, stream>>>((const unsigned*)ei, flag);
        hist_decode_kernel<<<egrid, 256, 0, stream>>>(ei, flag, degc, dr, n_edges, n_nodes);
        scan_partial_kernel<<<nparts, 256, 0, stream>>>(degc, part, n_nodes);
        scan_top_kernel<<<1, 512, 0, stream>>>(part, nparts);
        scan_final_kernel<<<nparts, 256, 0, stream>>>(degc, part, offs, dinv, n_nodes);
        cast_x_kernel<<<(n4 + 255) / 256, 256, 0, stream>>>(x, xb, n4);
        cast_w_kernel<<<16, 256, 0, stream>>>(W1l, W1r, W2l, W2r, wb);
        scatter_xcd_kernel<<<8 * 1024, 256, 0, stream>>>(ei, flag, dr, offs, csr, n_edges, n_nodes);
        gather_bf16_kernel<<<ggrid, 256, 0, stream>>>(xb, offs, degc, dinv, csr, agg, n_nodes);
        gemm_l1b_kernel<<<mgrid, 256, 0, stream>>>(agg, xb, wb, wb + 4096, b1, h, n_nodes);
        gather_bf16_kernel<<<ggrid, 256, 0, stream>>>(h, offs, degc, dinv, csr, agg, n_nodes);
        gemm_l2_kernel<<<mgrid, 256, 0, stream>>>(agg, h, wb + 8192, wb + 12288, b2, out, n_nodes);
    } else if (ws_size >= needT3) {
        zero2_kernel<<<nparts, 256, 0, stream>>>(degc3, cursor3, n_nodes);
        detect_idx_kernel<<<1, 256, 0, stream>>>((const unsigned*)ei, flag3);
        hist_kernel<<<egrid, 256, 0, stream>>>(ei, flag3, degc3, n_edges, n_nodes);
        scan_partial_kernel<<<nparts, 256, 0, stream>>>(degc3, part3, n_nodes);
        scan_top_kernel<<<1, 512, 0, stream>>>(part3, nparts);
        scan_final_kernel<<<nparts, 256, 0, stream>>>(degc3, part3, offs3, dinv3, n_nodes);
        csr_scatter_kernel<<<egrid, 256, 0, stream>>>(ei, flag3, offs3, cursor3, csr3, n_edges, n_nodes);
        cast_w_kernel<<<16, 256, 0, stream>>>(W1l, W1r, W2l, W2r, wb3);
        gather_f32_kernel<<<ggrid, 256, 0, stream>>>(x, offs3, degc3, dinv3, csr3, agg3, n_nodes);
        gemm_l1_kernel<<<mgrid, 256, 0, stream>>>(agg3, x, wb3, wb3 + 4096, b1, h3, n_nodes);
        gather_bf16_kernel<<<ggrid, 256, 0, stream>>>(h3, offs3, degc3, dinv3, csr3, agg3, n_nodes);
        gemm_l2_kernel<<<mgrid, 256, 0, stream>>>(agg3, h3, wb3 + 8192, wb3 + 12288, b2, out, n_nodes);
    } else {
        __bf16* hf = (__bf16*)(ws + commonEnd3);
        zero2_kernel<<<nparts, 256, 0, stream>>>(degc3, cursor3, n_nodes);
        detect_idx_kernel<<<1, 256, 0, stream>>>((const unsigned*)ei, flag3);
        hist_kernel<<<egrid, 256, 0, stream>>>(ei, flag3, degc3, n_edges, n_nodes);
        scan_partial_kernel<<<nparts, 256, 0, stream>>>(degc3, part3, n_nodes);
        scan_top_kernel<<<1, 512, 0, stream>>>(part3, nparts);
        scan_final_kernel<<<nparts, 256, 0, stream>>>(degc3, part3, offs3, dinv3, n_nodes);
        csr_scatter_kernel<<<egrid, 256, 0, stream>>>(ei, flag3, offs3, cursor3, csr3, n_edges, n_nodes);
        const int n_groups = (n_nodes + 3) / 4;
        const int fgrid = n_groups < 4096 ? n_groups : 4096;
        sage_fused_l1_kernel<<<fgrid, 256, 0, stream>>>(x, offs3, degc3, dinv3, csr3,
                                                        W1l, b1, W1r, hf, n_nodes);
        sage_fused_l2_kernel<<<fgrid, 256, 0, stream>>>(hf, offs3, degc3, dinv3, csr3,
                                                        W2l, b2, W2r, out, n_nodes);
    }
}